// Round 17
// baseline (341.486 us; speedup 1.0000x reference)
//
#include <hip/hip_runtime.h>

#define KNB 16
#define BSZ 8
#define NPT 2048

typedef __attribute__((ext_vector_type(8))) short bf16x8;
typedef __attribute__((ext_vector_type(4))) float f32x4;

// lrelu = max(x, 0.01x): exact for all x, 2 VALU ops (vs cmp+cndmask 3).
__device__ __forceinline__ float lrelu(float x) { return fmaxf(x, 0.01f * x); }

__device__ __forceinline__ unsigned short bf16rne(float f) {
    union { float f; unsigned int u; } v; v.f = f;
    return (unsigned short)((v.u + 0x7FFFu + ((v.u >> 16) & 1u)) >> 16);
}

// pack 2 f32 -> 2 bf16 (lo | hi<<16), RNE — single VALU op, bit-identical
// to bf16rne pair (R23).
__device__ __forceinline__ unsigned int cvt_pk_bf16(float lo, float hi) {
    unsigned int r;
    asm("v_cvt_pk_bf16_f32 %0, %1, %2" : "=v"(r) : "v"(lo), "v"(hi));
    return r;
}

// pack candidate index into low 11 mantissa bits of fp32 score -> unique,
// float-comparable key. idx = bits & 2047.
__device__ __forceinline__ float packkey(float d, int idx) {
    union { float f; unsigned int u; } v; v.f = d;
    v.u = (v.u & 0xFFFFF800u) | (unsigned int)idx;
    return v.f;
}

// ---------------------------------------------------------------------------
// Branch-free top-16 primitives (R15). Keys unique -> no stability issues.
// ---------------------------------------------------------------------------
__device__ __forceinline__ void ceA(float& a, float& b) {
    const float lo = fminf(a, b), hi = fmaxf(a, b);
    a = lo; b = hi;
}

// bitonic sort 16 in-register, ascending. 80 CE = 160 min/max, depth 10.
__device__ __forceinline__ void bsort16(float* c) {
#pragma unroll
    for (int k = 2; k <= 16; k <<= 1) {
#pragma unroll
        for (int j = k >> 1; j > 0; j >>= 1) {
#pragma unroll
            for (int i = 0; i < 16; ++i) {
                const int l = i ^ j;
                if (l > i) {
                    if ((i & k) == 0) ceA(c[i], c[l]);
                    else              ceA(c[l], c[i]);
                }
            }
        }
    }
}

// L sorted asc, C sorted asc -> L = 16 smallest of union, sorted asc.
__device__ __forceinline__ void merge16(float* L, const float* C) {
#pragma unroll
    for (int i = 0; i < 16; ++i) L[i] = fminf(L[i], C[15 - i]);
#pragma unroll
    for (int j = 8; j > 0; j >>= 1) {
#pragma unroll
        for (int i = 0; i < 16; ++i) {
            const int l = i ^ j;
            if (l > i) ceA(L[i], L[l]);
        }
    }
}

__device__ __forceinline__ void st16(float* dst, const float* L) {
#pragma unroll
    for (int c = 0; c < 4; ++c)
        *(f32x4*)(dst + c * 4) = (f32x4){L[c * 4], L[c * 4 + 1], L[c * 4 + 2], L[c * 4 + 3]};
}

__device__ __forceinline__ void ld16(float* L, const float* src) {
#pragma unroll
    for (int c = 0; c < 4; ++c) {
        const f32x4 v = *(const f32x4*)(src + c * 4);
        L[c * 4] = v[0]; L[c * 4 + 1] = v[1]; L[c * 4 + 2] = v[2]; L[c * 4 + 3] = v[3];
    }
}

// cross-wave merge of 4 sorted lists (rows = lanes) + writeout by wave 0.
__device__ __forceinline__ void xwave_merge_out(float (*sS)[20], int w, int lane,
                                                float* L, float* outp) {
    st16(sS[w * 64 + lane], L);
    __syncthreads();
    if ((w & 1) == 0) {
        float C[16];
        ld16(C, sS[(w + 1) * 64 + lane]);
        merge16(L, C);
        if (w == 2) st16(sS[2 * 64 + lane], L);
    }
    __syncthreads();
    if (w == 0) {
        float C[16];
        ld16(C, sS[2 * 64 + lane]);
        merge16(L, C);
        st16(outp, L);
    }
}

// ---------------------------------------------------------------------------
// Merged weight prep (R18).
// ---------------------------------------------------------------------------
__global__ void wprep_all_kernel(const float* __restrict__ h2w1, unsigned short* __restrict__ w1t,
                                 const float* __restrict__ h2w2, unsigned short* __restrict__ w2t,
                                 const float* __restrict__ h3w1, unsigned short* __restrict__ w3t,
                                 const float* __restrict__ w1, const float* __restrict__ w2,
                                 const float* __restrict__ w3,
                                 unsigned short* __restrict__ w1a, unsigned short* __restrict__ w2a,
                                 unsigned short* __restrict__ w3a) {
    const int bid = blockIdx.x, tid = threadIdx.x;
    if (bid < 64) {
        int i = bid * 256 + tid;                 // K=64, N=256
        int k = i >> 8, n = i & 255;
        w1t[n * 64 + k] = bf16rne(h2w1[i]);
    } else if (bid < 192) {
        int i = (bid - 64) * 256 + tid;          // K=256, N=128
        int k = i >> 7, n = i & 127;
        w2t[n * 256 + k] = bf16rne(h2w2[i]);
    } else if (bid < 320) {
        int i = (bid - 192) * 256 + tid;
        int k = i >> 7, n = i & 127;
        w3t[n * 256 + k] = bf16rne(h3w1[i]);
    } else {
        int i = (bid - 320) * 256 + tid;
        if (i < 512) {
            int n = i >> 5, k = i & 31;
            w1a[i] = (k < 6) ? bf16rne(w1[k * 16 + n]) : (unsigned short)0;
        } else if (i < 2560) {
            int j = i - 512, n = j >> 5, k = j & 31;
            w2a[j] = (k < 16) ? bf16rne(w2[k * 64 + n]) : (unsigned short)0;
        } else if (i < 4608) {
            int j = i - 2560, n = j >> 6, k = j & 63;
            w3a[j] = bf16rne(w3[k * 32 + n]);
        }
    }
}

// ---------------------------------------------------------------------------
// Per-point squared norms (x only; x2/x3 norms are fused into block1/block2)
// ---------------------------------------------------------------------------
template<int C>
__global__ void norms_kernel(const float* __restrict__ feat, float* __restrict__ out) {
    int gid = blockIdx.x * blockDim.x + threadIdx.x;
    if (gid < BSZ * NPT) {
        const float* p = feat + (size_t)gid * C;
        float s = 0.f;
#pragma unroll
        for (int c = 0; c < C; ++c) s = fmaf(p[c], p[c], s);
        out[gid] = s;
    }
}

// ---------------------------------------------------------------------------
// KNN C=3, fp32 (R20 XCD-batch swizzle).
// ---------------------------------------------------------------------------
template<int JS>
__launch_bounds__(256, 4)
__global__ void knn3_kernel(const float* __restrict__ feat,
                            const float* __restrict__ norms,
                            float* __restrict__ cand) {
    constexpr int JL = NPT / JS;
    constexpr int JP = JL / 4;
    const int idxf = blockIdx.x + 32 * (blockIdx.y + 8 * blockIdx.z);
    const int b    = idxf & 7;
    const int rem  = idxf >> 3;          // 0..255
    const int js   = rem & 7;
    const int i0   = (rem >> 3) * 64;
    const int t = threadIdx.x, w = t >> 6, lane = t & 63;
    const float* fb = feat + (size_t)b * NPT * 3;
    const float* nb = norms + (size_t)b * NPT;

    __shared__ __align__(16) float sS[256][20];

    float q0, q1, q2;
    { const float* qp = fb + (size_t)(i0 + lane) * 3; q0 = qp[0]; q1 = qp[1]; q2 = qp[2]; }

    float L[16];
    const int jbeg = js * JL + w * JP;
#pragma unroll 1
    for (int j0 = jbeg; j0 < jbeg + JP; j0 += 16) {
        float C[16];
#pragma unroll
        for (int u = 0; u < 16; ++u) {
            const int j = j0 + u;
            const float* pp = fb + (size_t)j * 3;
            C[u] = packkey(fmaf(-2.f, fmaf(q0, pp[0], fmaf(q1, pp[1], q2 * pp[2])), nb[j]), j);
        }
        bsort16(C);
        if (j0 == jbeg) {
#pragma unroll
            for (int u = 0; u < 16; ++u) L[u] = C[u];
        } else {
            merge16(L, C);
        }
    }
    float* o = cand + (((size_t)b * NPT + i0 + lane) * JS + js) * 16;
    xwave_merge_out(sS, w, lane, L, o);
}

// ---------------------------------------------------------------------------
// KNN via bf16 MFMA (R20 XCD-batch swizzle). R23: C=128 stages the shared
// 64x128 query tile in LDS once. R29: same dedup for C=32 (neutral, kept).
// ---------------------------------------------------------------------------
template<int C, int JS>
__launch_bounds__(256, C == 32 ? 4 : 3)
__global__ void knn_mfma_kernel(const unsigned short* __restrict__ fb16,
                                const float* __restrict__ norms,
                                float* __restrict__ cand) {
    constexpr int JL = NPT / JS;
    constexpr int KS = C / 32;
    const int idxf = blockIdx.x + 32 * (blockIdx.y + 8 * blockIdx.z);
    const int b    = idxf & 7;
    const int rem  = idxf >> 3;          // 0..255
    const int js   = rem & 7;
    const int i0   = (rem >> 3) * 64;
    const int t    = threadIdx.x;
    const int w    = t >> 6;
    const int lane = t & 63;
    const int l15  = lane & 15;
    const int quad = lane >> 4;
    const unsigned short* fbb = fb16 + (size_t)b * NPT * C;
    const float* nb = norms + (size_t)b * NPT;

    __shared__ __align__(16) float sS[256][20];

    bf16x8 afr[KS * 4];
    if constexpr (C == 128) {
        __shared__ __align__(16) unsigned short sAF[64][132];   // 16896 B
        {
            const int row = t >> 2, c4 = t & 3;
#pragma unroll
            for (int c = 0; c < 4; ++c) {
                const int chunk = c4 * 4 + c;
                *(bf16x8*)&sAF[row][chunk * 8] =
                    *(const bf16x8*)(fbb + (size_t)(i0 + row) * 128 + chunk * 8);
            }
        }
        __syncthreads();
#pragma unroll
        for (int ks = 0; ks < KS; ++ks)
#pragma unroll
            for (int mi = 0; mi < 4; ++mi)
                afr[ks * 4 + mi] = *(const bf16x8*)&sAF[mi * 16 + l15][ks * 32 + quad * 8];
    } else {
        // R29: stage 64x32 query tile once (256 threads x 16B = 4KB)
        __shared__ __align__(16) unsigned short sQ[64][40];     // 5120 B
        {
            const int row = t >> 2, c4 = t & 3;
            *(bf16x8*)&sQ[row][c4 * 8] =
                *(const bf16x8*)(fbb + (size_t)(i0 + row) * 32 + c4 * 8);
        }
        __syncthreads();
#pragma unroll
        for (int mi = 0; mi < 4; ++mi)
            afr[mi] = *(const bf16x8*)&sQ[mi * 16 + l15][quad * 8];
    }

    float L[16];
    const int jbeg = js * JL;
#pragma unroll 1
    for (int j0 = jbeg; j0 < jbeg + JL; j0 += 64) {
        f32x4 acc[4];
#pragma unroll
        for (int mi = 0; mi < 4; ++mi) acc[mi] = (f32x4){0.f, 0.f, 0.f, 0.f};
        const unsigned short* prow = fbb + (size_t)(j0 + w * 16 + l15) * C + quad * 8;
#pragma unroll
        for (int ks = 0; ks < KS; ++ks) {
            const bf16x8 bfr = *(const bf16x8*)(prow + ks * 32);
#pragma unroll
            for (int mi = 0; mi < 4; ++mi)
                acc[mi] = __builtin_amdgcn_mfma_f32_16x16x32_bf16(afr[ks * 4 + mi], bfr, acc[mi], 0, 0, 0);
        }
        const float nv  = nb[j0 + w * 16 + l15];
        const int  cidx = j0 + w * 16 + l15;
        // D layout: col(candidate)=l15, row(query)=mi*16+quad*4+r. Write
        // packed keys to this wave's private strip; read back transposed.
#pragma unroll
        for (int mi = 0; mi < 4; ++mi)
#pragma unroll
            for (int r = 0; r < 4; ++r)
                sS[w * 64 + mi * 16 + quad * 4 + r][l15] = packkey(fmaf(-2.f, acc[mi][r], nv), cidx);
        float Cb[16];
        ld16(Cb, sS[w * 64 + lane]);
        bsort16(Cb);
        if (j0 == jbeg) {
#pragma unroll
            for (int u = 0; u < 16; ++u) L[u] = Cb[u];
        } else {
            merge16(L, Cb);
        }
    }

    float* o = cand + (((size_t)b * NPT + i0 + lane) * JS + js) * 16;
    xwave_merge_out(sS, w, lane, L, o);
}

// ---------------------------------------------------------------------------
// Merge JS sorted packed-key lists per query -> final top-16 indices.
// ---------------------------------------------------------------------------
template<int JS>
__launch_bounds__(64)
__global__ void knn_merge_kernel(const float* __restrict__ cand, int* __restrict__ knn_out) {
    const int q = blockIdx.x * 64 + threadIdx.x;
    const float* pd = cand + (size_t)q * JS * 16;
    float L[16];
    ld16(L, pd);
#pragma unroll
    for (int s = 1; s < JS; ++s) {
        float C[16];
        ld16(C, pd + s * 16);
        merge16(L, C);
    }
    int* o = knn_out + (size_t)q * KNB;
#pragma unroll
    for (int u = 0; u < 16; ++u) {
        union { float f; unsigned int v; } z; z.f = L[u];
        o[u] = (int)(z.v & 2047u);
    }
}

// ---------------------------------------------------------------------------
// Block 1 via MFMA, swapped operands (R18) + fused x2 norm.
// R23: bf16 packing via v_cvt_pk_bf16_f32 (1 op per pair, bit-identical).
// ---------------------------------------------------------------------------
__launch_bounds__(256, 3)
__global__ void block1_mfma_kernel(const float* __restrict__ x, const int* __restrict__ knn,
                                   const unsigned short* __restrict__ w1a, const float* __restrict__ b1,
                                   const unsigned short* __restrict__ w2a, const float* __restrict__ b2,
                                   const unsigned short* __restrict__ w3a, const float* __restrict__ b3,
                                   unsigned short* __restrict__ x2b, float* __restrict__ nrm) {
    const int w = threadIdx.x >> 6, lane = threadIdx.x & 63;
    const int l15 = lane & 15, quad = lane >> 4;

    const bf16x8 W1 = *(const bf16x8*)(w1a + l15 * 32 + quad * 8);
    bf16x8 W2[4];
#pragma unroll
    for (int nt = 0; nt < 4; ++nt)
        W2[nt] = *(const bf16x8*)(w2a + (nt * 16 + l15) * 32 + quad * 8);
    bf16x8 W3[2][2];
#pragma unroll
    for (int tt = 0; tt < 2; ++tt)
#pragma unroll
        for (int ks = 0; ks < 2; ++ks)
            W3[tt][ks] = *(const bf16x8*)(w3a + (tt * 16 + l15) * 64 + ks * 32 + quad * 8);
    float b1v[4], b2v[4][4], b3v[2][4];
#pragma unroll
    for (int r = 0; r < 4; ++r) b1v[r] = b1[quad * 4 + r];
#pragma unroll
    for (int nt = 0; nt < 4; ++nt)
#pragma unroll
        for (int r = 0; r < 4; ++r) b2v[nt][r] = b2[nt * 16 + quad * 4 + r];
#pragma unroll
    for (int tt = 0; tt < 2; ++tt)
#pragma unroll
        for (int r = 0; r < 4; ++r) b3v[tt][r] = b3[tt * 16 + quad * 4 + r];

    const int src0 = ((2 * quad) & 3) * 16 + l15;
    const int src1 = ((2 * quad + 1) & 3) * 16 + l15;
    const int ntsel = quad >> 1;

    const int p0 = blockIdx.x * 8 + w * 2;
#pragma unroll 2
    for (int pi = 0; pi < 2; ++pi) {
        const int p = p0 + pi, b = p >> 11, n = p & (NPT - 1);
        int d0 = 0, d1 = 0, d2 = 0;
        if (quad == 0) {
            const float* xc = x + ((size_t)b * NPT + n) * 3;
            const int jn = knn[(size_t)p * KNB + l15];
            const float* xn = x + ((size_t)b * NPT + jn) * 3;
            const unsigned s0 = bf16rne(xc[0]), s1 = bf16rne(xc[1]), s2 = bf16rne(xc[2]);
            const unsigned s3 = bf16rne(xn[0]), s4 = bf16rne(xn[1]), s5 = bf16rne(xn[2]);
            d0 = (int)(s0 | (s1 << 16));
            d1 = (int)(s2 | (s3 << 16));
            d2 = (int)(s4 | (s5 << 16));
        }
        union { int i[4]; bf16x8 v; } B1;
        B1.i[0] = d0; B1.i[1] = d1; B1.i[2] = d2; B1.i[3] = 0;
        const f32x4 a1 = __builtin_amdgcn_mfma_f32_16x16x32_bf16(W1, B1.v, (f32x4){0.f, 0.f, 0.f, 0.f}, 0, 0, 0);

        const int h10 = (int)cvt_pk_bf16(lrelu(a1[0] + b1v[0]), lrelu(a1[1] + b1v[1]));
        const int h11 = (int)cvt_pk_bf16(lrelu(a1[2] + b1v[2]), lrelu(a1[3] + b1v[3]));
        union { int i[4]; bf16x8 v; } B2;
        {
            const int e0 = __shfl(h10, src0), e1 = __shfl(h11, src0);
            const int e2 = __shfl(h10, src1), e3 = __shfl(h11, src1);
            const bool val = quad < 2;
            B2.i[0] = val ? e0 : 0; B2.i[1] = val ? e1 : 0;
            B2.i[2] = val ? e2 : 0; B2.i[3] = val ? e3 : 0;
        }
        f32x4 a2[4];
#pragma unroll
        for (int nt = 0; nt < 4; ++nt)
            a2[nt] = __builtin_amdgcn_mfma_f32_16x16x32_bf16(W2[nt], B2.v, (f32x4){0.f, 0.f, 0.f, 0.f}, 0, 0, 0);
        int dpk[4][2];
#pragma unroll
        for (int nt = 0; nt < 4; ++nt) {
            dpk[nt][0] = (int)cvt_pk_bf16(lrelu(a2[nt][0] + b2v[nt][0]), lrelu(a2[nt][1] + b2v[nt][1]));
            dpk[nt][1] = (int)cvt_pk_bf16(lrelu(a2[nt][2] + b2v[nt][2]), lrelu(a2[nt][3] + b2v[nt][3]));
        }
        f32x4 a3[2] = { (f32x4){0.f, 0.f, 0.f, 0.f}, (f32x4){0.f, 0.f, 0.f, 0.f} };
#pragma unroll
        for (int ks = 0; ks < 2; ++ks) {
            union { int i[4]; bf16x8 v; } B3;
            const int a0l = __shfl(dpk[2 * ks][0], src0), a0h = __shfl(dpk[2 * ks + 1][0], src0);
            const int a1l = __shfl(dpk[2 * ks][1], src0), a1h = __shfl(dpk[2 * ks + 1][1], src0);
            const int a2l = __shfl(dpk[2 * ks][0], src1), a2h = __shfl(dpk[2 * ks + 1][0], src1);
            const int a3l = __shfl(dpk[2 * ks][1], src1), a3h = __shfl(dpk[2 * ks + 1][1], src1);
            B3.i[0] = ntsel ? a0h : a0l;
            B3.i[1] = ntsel ? a1h : a1l;
            B3.i[2] = ntsel ? a2h : a2l;
            B3.i[3] = ntsel ? a3h : a3l;
#pragma unroll
            for (int tt = 0; tt < 2; ++tt)
                a3[tt] = __builtin_amdgcn_mfma_f32_16x16x32_bf16(W3[tt][ks], B3.v, a3[tt], 0, 0, 0);
        }
        float na = 0.f;
#pragma unroll
        for (int tt = 0; tt < 2; ++tt) {
#pragma unroll
            for (int r = 0; r < 4; ++r) {
                float s = lrelu(a3[tt][r] + b3v[tt][r]);
                s += __shfl_xor(s, 1);
                s += __shfl_xor(s, 2);
                s += __shfl_xor(s, 4);
                s += __shfl_xor(s, 8);
                na = fmaf(s, s, na);                      // all lanes hold s
                if (l15 == 0)
                    x2b[(size_t)p * 32 + tt * 16 + quad * 4 + r] = bf16rne(s);
            }
        }
        // fused norm: na is quad-partial (8 channels), identical across l15
        na += __shfl_xor(na, 16);
        na += __shfl_xor(na, 32);
        if (lane == 0) nrm[p] = na;
    }
}

// ---------------------------------------------------------------------------
// Block 2 fused, weight-stationary, 8-wave, LDS-staged gathers (R22),
// operand-swapped L1 + pad-buffer tail (R25), (512,4) optimum (R28),
// paired points + 4 sH1 buffers (R30: barriers 17 -> 10, +2.8us).
// ---------------------------------------------------------------------------
__launch_bounds__(512, 4)
__global__ void block2_fused_kernel(const unsigned short* __restrict__ x2b,
                                    const int* __restrict__ knn,
                                    const unsigned short* __restrict__ w1t,  // [256][64]
                                    const float* __restrict__ b1,
                                    const unsigned short* __restrict__ w2t,  // [128][256]
                                    const float* __restrict__ b2,
                                    unsigned short* __restrict__ x3b,
                                    float* __restrict__ nrm2) {
    const int w    = threadIdx.x >> 6;        // 0..7
    const int lane = threadIdx.x & 63;
    const int l15  = lane & 15, quad = lane >> 4;
    __shared__ __align__(16) unsigned short sH1[4][16][264];   // 33792 B
    __shared__ __align__(16) unsigned short sA2[16][17][40];   // 21760 B (pads = us buffer)

    bf16x8 B1[2][2];
#pragma unroll
    for (int nt2 = 0; nt2 < 2; ++nt2)
#pragma unroll
        for (int ks = 0; ks < 2; ++ks)
            B1[nt2][ks] = *(const bf16x8*)(w1t + (size_t)(w * 32 + nt2 * 16 + l15) * 64 + ks * 32 + quad * 8);
    bf16x8 B2[8];
#pragma unroll
    for (int ks = 0; ks < 8; ++ks)
        B2[ks] = *(const bf16x8*)(w2t + (size_t)(w * 16 + l15) * 256 + ks * 32 + quad * 8);
    // bias indexed by D-row (quad*4+r) after operand swap
    float bA[2][4];
#pragma unroll
    for (int nt2 = 0; nt2 < 2; ++nt2)
#pragma unroll
        for (int r = 0; r < 4; ++r) bA[nt2][r] = b1[w * 32 + nt2 * 16 + quad * 4 + r];
    const float b2v = b2[w * 16 + l15];

    const int src = (blockIdx.x & 7) * 128 + (blockIdx.x >> 3);   // XCD-batch swizzle
    const int p0 = src * 16;                             // 16 points, same batch
    const unsigned short* xb = x2b + (size_t)(p0 >> 11) * NPT * 32;

    // ---- stage: wave w loads points 2w, 2w+1's rows into LDS, once --------
    {
        const int pA = p0 + 2 * w, pB = pA + 1;
        const int nA = knn[(size_t)pA * KNB + l15];
        const int nB = knn[(size_t)pB * KNB + l15];
        *(bf16x8*)&sA2[2 * w][l15][quad * 8] =
            *(const bf16x8*)(xb + (size_t)nA * 32 + quad * 8);
        *(bf16x8*)&sA2[2 * w + 1][l15][quad * 8] =
            *(const bf16x8*)(xb + (size_t)nB * 32 + quad * 8);
        if (l15 == 0) {
            *(bf16x8*)&sA2[2 * w][16][quad * 8] =
                *(const bf16x8*)(x2b + (size_t)pA * 32 + quad * 8);
            *(bf16x8*)&sA2[2 * w + 1][16][quad * 8] =
                *(const bf16x8*)(x2b + (size_t)pB * 32 + quad * 8);
        }
    }
    __syncthreads();                                     // sA2 ready (cols 0..31 read-only after)

    const int nrow = (w * 16 + l15) >> 3;                // pad row for this lane's channel
    const int ncol = 32 + (l15 & 7);                     // pad col

#pragma unroll 1
    for (int pp = 0; pp < 8; ++pp) {
        const int bufA = (pp & 1) * 2, bufB = bufA + 1;  // pairs {0,1} / {2,3}
        const int piA = 2 * pp, piB = piA + 1;

        // ---- L1 phase: both points of the pair (independent MFMA work) ----
        {
            const bf16x8 a0 = *(const bf16x8*)&sA2[piA][16][quad * 8];
            const bf16x8 a1 = *(const bf16x8*)&sA2[piA][l15][quad * 8];
#pragma unroll
            for (int nt2 = 0; nt2 < 2; ++nt2) {
                f32x4 acc = (f32x4){0.f, 0.f, 0.f, 0.f};
                acc = __builtin_amdgcn_mfma_f32_16x16x32_bf16(B1[nt2][0], a0, acc, 0, 0, 0);
                acc = __builtin_amdgcn_mfma_f32_16x16x32_bf16(B1[nt2][1], a1, acc, 0, 0, 0);
                const unsigned int u01 = cvt_pk_bf16(lrelu(acc[0] + bA[nt2][0]), lrelu(acc[1] + bA[nt2][1]));
                const unsigned int u23 = cvt_pk_bf16(lrelu(acc[2] + bA[nt2][2]), lrelu(acc[3] + bA[nt2][3]));
                union { unsigned int u[2]; unsigned long long ull; } pk;
                pk.u[0] = u01; pk.u[1] = u23;
                *(unsigned long long*)&sH1[bufA][l15][w * 32 + nt2 * 16 + quad * 4] = pk.ull;
            }
        }
        {
            const bf16x8 a0 = *(const bf16x8*)&sA2[piB][16][quad * 8];
            const bf16x8 a1 = *(const bf16x8*)&sA2[piB][l15][quad * 8];
#pragma unroll
            for (int nt2 = 0; nt2 < 2; ++nt2) {
                f32x4 acc = (f32x4){0.f, 0.f, 0.f, 0.f};
                acc = __builtin_amdgcn_mfma_f32_16x16x32_bf16(B1[nt2][0], a0, acc, 0, 0, 0);
                acc = __builtin_amdgcn_mfma_f32_16x16x32_bf16(B1[nt2][1], a1, acc, 0, 0, 0);
                const unsigned int u01 = cvt_pk_bf16(lrelu(acc[0] + bA[nt2][0]), lrelu(acc[1] + bA[nt2][1]));
                const unsigned int u23 = cvt_pk_bf16(lrelu(acc[2] + bA[nt2][2]), lrelu(acc[3] + bA[nt2][3]));
                union { unsigned int u[2]; unsigned long long ull; } pk;
                pk.u[0] = u01; pk.u[1] = u23;
                *(unsigned long long*)&sH1[bufB][l15][w * 32 + nt2 * 16 + quad * 4] = pk.ull;
            }
        }

        __syncthreads();                                 // ONE barrier per pair

        // ---- L2 phase: both points (sequential, register reuse) -----------
        {
            bf16x8 afA[4], afB[4];
#pragma unroll
            for (int ks = 0; ks < 4; ++ks)
                afA[ks] = *(const bf16x8*)&sH1[bufA][l15][ks * 32 + quad * 8];
#pragma unroll
            for (int ks = 0; ks < 4; ++ks)
                afB[ks] = *(const bf16x8*)&sH1[bufA][l15][128 + ks * 32 + quad * 8];
            f32x4 accA = (f32x4){0.f, 0.f, 0.f, 0.f}, accB = (f32x4){0.f, 0.f, 0.f, 0.f};
#pragma unroll
            for (int ks = 0; ks < 4; ++ks) {
                accA = __builtin_amdgcn_mfma_f32_16x16x32_bf16(afA[ks], B2[ks], accA, 0, 0, 0);
                accB = __builtin_amdgcn_mfma_f32_16x16x32_bf16(afB[ks], B2[4 + ks], accB, 0, 0, 0);
            }
            float s = 0.f;
#pragma unroll
            for (int r = 0; r < 4; ++r) s += lrelu(accA[r] + accB[r] + b2v);
            s += __shfl_xor(s, 16);
            s += __shfl_xor(s, 32);
            const unsigned short us = bf16rne(s);
            if (quad == 0) sA2[piA][nrow][ncol] = us;     // us -> dead pad bytes
        }
        {
            bf16x8 afA[4], afB[4];
#pragma unroll
            for (int ks = 0; ks < 4; ++ks)
                afA[ks] = *(const bf16x8*)&sH1[bufB][l15][ks * 32 + quad * 8];
#pragma unroll
            for (int ks = 0; ks < 4; ++ks)
                afB[ks] = *(const bf16x8*)&sH1[bufB][l15][128 + ks * 32 + quad * 8];
            f32x4 accA = (f32x4){0.f, 0.f, 0.f, 0.f}, accB = (f32x4){0.f, 0.f, 0.f, 0.f};
#pragma unroll
            for (int ks = 0; ks < 4; ++ks) {
                accA = __builtin_amdgcn_mfma_f32_16x16x32_bf16(afA[ks], B2[ks], accA, 0, 0, 0);
                accB = __builtin_amdgcn_mfma_f32_16x16x32_bf16(afB[ks], B2[4 + ks], accB, 0, 0, 0);
            }
            float s = 0.f;
#pragma unroll
            for (int r = 0; r < 4; ++r) s += lrelu(accA[r] + accB[r] + b2v);
            s += __shfl_xor(s, 16);
            s += __shfl_xor(s, 32);
            const unsigned short us = bf16rne(s);
            if (quad == 0) sA2[piB][nrow][ncol] = us;     // us -> dead pad bytes
        }
    }

    // ---- tail: x3b store (b128) + x3 norm, both from sA2 pads -------------
    __syncthreads();
    if (threadIdx.x < 256) {
        const int pi = threadIdx.x >> 4, seg = threadIdx.x & 15;
        const bf16x8 v = *(const bf16x8*)&sA2[pi][seg][32];   // 8 ch, b128, aligned
        *(bf16x8*)&x3b[(size_t)(p0 + pi) * 128 + seg * 8] = v;
        float s = 0.f;
#pragma unroll
        for (int j = 0; j < 8; ++j) {
            union { unsigned int u; float f; } t;
            t.u = ((unsigned int)(unsigned short)v[j]) << 16;
            s = fmaf(t.f, t.f, s);
        }
        s += __shfl_xor(s, 1);
        s += __shfl_xor(s, 2);
        s += __shfl_xor(s, 4);
        s += __shfl_xor(s, 8);
        if (seg == 0) nrm2[p0 + pi] = s;
    }
}

// ---------------------------------------------------------------------------
// Block 3 fused, R21 LDS-staged gathers. R31: MAXPOOL FUSED — x4 is consumed
// ONLY by the maxpool; every lane already holds the final s for its channel
// at each of the block's 8 points, so a running fmaxf across pi gives the
// per-block per-channel max for free. Writes a single 128-float partial-max
// row (part[src][ch]) instead of 8x128 x4 floats; maxpool kernel deleted.
// fmaxf is exact -> head2's max over 256 block-partials is bit-identical.
// ---------------------------------------------------------------------------
__launch_bounds__(512, 4)
__global__ void block3_fused_kernel(const unsigned short* __restrict__ x3b,
                                    const int* __restrict__ knn,
                                    const unsigned short* __restrict__ w3t,  // [128][256]
                                    const float* __restrict__ bias,
                                    float* __restrict__ part) {
    const int w    = threadIdx.x >> 6;        // 0..7
    const int lane = threadIdx.x & 63;
    const int l15  = lane & 15, quad = lane >> 4;
    // sA[point][row 0..15 = nbr l15, row 16 = center][132 shorts]
    __shared__ __align__(16) unsigned short sA[8][17][132];   // 35904 B

    bf16x8 B3[8];
#pragma unroll
    for (int ks = 0; ks < 8; ++ks)
        B3[ks] = *(const bf16x8*)(w3t + (size_t)(w * 16 + l15) * 256 + ks * 32 + quad * 8);
    const float bv = bias[w * 16 + l15];

    const int src = (blockIdx.x & 7) * 256 + (blockIdx.x >> 3);   // XCD-batch swizzle (2048 blocks)
    const int p0 = src * 8;                              // 8 points, same batch
    const unsigned short* xb = x3b + (size_t)(p0 >> 11) * NPT * 128;

    // ---- stage: wave w loads point (p0+w)'s rows into LDS, exactly once ----
    {
        const int p = p0 + w;
        const int nbr = knn[(size_t)p * KNB + l15];
        const unsigned short* nrow = xb + (size_t)nbr * 128;
#pragma unroll
        for (int c = 0; c < 4; ++c) {
            const bf16x8 v = *(const bf16x8*)(nrow + (c * 4 + quad) * 8);
            *(bf16x8*)&sA[w][l15][(c * 4 + quad) * 8] = v;
        }
        if (quad == 0) {
            const bf16x8 v = *(const bf16x8*)(x3b + (size_t)p * 128 + l15 * 8);
            *(bf16x8*)&sA[w][16][l15 * 8] = v;
        }
    }
    __syncthreads();                                     // the only barrier

    // ---- compute: every wave does its 16 channels for all 8 points,
    //      keeping only the running max (R31) ------------------------------
    float mx = -1e30f;
#pragma unroll 2
    for (int pi = 0; pi < 8; ++pi) {
        bf16x8 afA[4], afB[4];
#pragma unroll
        for (int ks = 0; ks < 4; ++ks) {
            afA[ks] = *(const bf16x8*)&sA[pi][16][(ks * 4 + quad) * 8];    // center (broadcast)
            afB[ks] = *(const bf16x8*)&sA[pi][l15][(ks * 4 + quad) * 8];   // neighbor rows
        }
        f32x4 accA = (f32x4){0.f, 0.f, 0.f, 0.f}, accB = (f32x4){0.f, 0.f, 0.f, 0.f};
#pragma unroll
        for (int ks = 0; ks < 4; ++ks) {
            accA = __builtin_amdgcn_mfma_f32_16x16x32_bf16(afA[ks], B3[ks], accA, 0, 0, 0);
            accB = __builtin_amdgcn_mfma_f32_16x16x32_bf16(afB[ks], B3[4 + ks], accB, 0, 0, 0);
        }
        float s = 0.f;
#pragma unroll
        for (int r = 0; r < 4; ++r) s += lrelu(accA[r] + accB[r] + bv);
        s += __shfl_xor(s, 16);
        s += __shfl_xor(s, 32);
        mx = fmaxf(mx, s);                               // all lanes hold s
    }
    if (quad == 0) part[(size_t)src * 128 + w * 16 + l15] = mx;
}

// ---------------------------------------------------------------------------
// Head stage 2 (R31: reduces 256 block-partials per batch; L2-resident 1MB)
// ---------------------------------------------------------------------------
__launch_bounds__(128)
__global__ void head2_kernel(const float* __restrict__ part,
                             const float* __restrict__ fc1w, const float* __restrict__ fc1b,
                             const float* __restrict__ fc2w, const float* __restrict__ fc2b,
                             const float* __restrict__ fc3w, const float* __restrict__ fc3b,
                             float* __restrict__ out) {
    const int g = blockIdx.x, b = blockIdx.y, t = threadIdx.x;
    __shared__ float s5[128], s6[128], s7[128];
    float m = -1e30f;
#pragma unroll 8
    for (int c = 0; c < 256; ++c)
        m = fmaxf(m, part[((size_t)b * 256 + c) * 128 + t]);
    s5[t] = m;
    __syncthreads();
    float a = fc1b[t];
#pragma unroll 4
    for (int i = 0; i < 128; ++i) a = fmaf(s5[i], fc1w[i * 128 + t], a);
    s6[t] = lrelu(a);
    __syncthreads();
    a = fc2b[t];
#pragma unroll 4
    for (int i = 0; i < 128; ++i) a = fmaf(s6[i], fc2w[i * 128 + t], a);
    s7[t] = lrelu(a);
    __syncthreads();
    const int o = g * 128 + t;
    float acc = fc3b[o];
#pragma unroll 4
    for (int i = 0; i < 128; ++i) acc = fmaf(s7[i], fc3w[(size_t)i * 6144 + o], acc);
    out[(size_t)b * 6144 + o] = acc;
}

// ---------------------------------------------------------------------------
extern "C" void kernel_launch(void* const* d_in, const int* in_sizes, int n_in,
                              void* d_out, int out_size, void* d_ws, size_t ws_size,
                              hipStream_t stream) {
    const float* x    = (const float*)d_in[0];
    const float* h1w1 = (const float*)d_in[1];
    const float* h1b1 = (const float*)d_in[2];
    const float* h1w2 = (const float*)d_in[3];
    const float* h1b2 = (const float*)d_in[4];
    const float* h1w3 = (const float*)d_in[5];
    const float* h1b3 = (const float*)d_in[6];
    const float* h2w1 = (const float*)d_in[7];
    const float* h2b1 = (const float*)d_in[8];
    const float* h2w2 = (const float*)d_in[9];
    const float* h2b2 = (const float*)d_in[10];
    const float* h3w1 = (const float*)d_in[11];
    const float* h3b1 = (const float*)d_in[12];
    const float* fc1w = (const float*)d_in[13];
    const float* fc1b = (const float*)d_in[14];
    const float* fc2w = (const float*)d_in[15];
    const float* fc2b = (const float*)d_in[16];
    const float* fc3w = (const float*)d_in[17];
    const float* fc3b = (const float*)d_in[18];

    float* ws = (float*)d_ws;
    unsigned short* x2b16 = (unsigned short*)ws;              //  524288 sh (262144 fl)
    unsigned short* x3b16 = (unsigned short*)(ws + 262144);   // 2097152 sh (1048576 fl)
    float* cd   = ws + 1310720;                               // 2097152 fl (knn candidates;
                                                              // x4 no longer exists — R31)
    int*   idx  = (int*)(ws + 3407872);                       //  262144 int
    float* nrm  = ws + 3670016;                               //   16384 fl
    unsigned short* w1t = (unsigned short*)(ws + 3702784);    //  16384 sh
    unsigned short* w2t = (unsigned short*)(ws + 3710976);    //  32768 sh
    unsigned short* w3t = (unsigned short*)(ws + 3727360);    //  32768 sh
    unsigned short* w1a = (unsigned short*)(ws + 3743744);    //    512 sh
    unsigned short* w2a = (unsigned short*)(ws + 3744000);    //   2048 sh
    unsigned short* w3a = (unsigned short*)(ws + 3745024);    //   2048 sh
    float* part = ws + 3746048;                               //  262144 fl (R31: 2048x128;
                                                              //  ends ~16.0 MB <= ws)
    float* out  = (float*)d_out;

    const dim3 kg(32, 8, 8);   // (qtile, j-split=8, batch) -> 2048 blocks

    wprep_all_kernel<<<338, 256, 0, stream>>>(h2w1, w1t, h2w2, w2t, h3w1, w3t,
                                              h1w1, h1w2, h1w3, w1a, w2a, w3a);

    norms_kernel<3><<<64, 256, 0, stream>>>(x, nrm);
    knn3_kernel<8><<<kg, 256, 0, stream>>>(x, nrm, cd);
    knn_merge_kernel<8><<<256, 64, 0, stream>>>(cd, idx);
    block1_mfma_kernel<<<2048, 256, 0, stream>>>(x, idx, w1a, h1b1, w2a, h1b2, w3a, h1b3,
                                                 x2b16, nrm);

    knn_mfma_kernel<32, 8><<<kg, 256, 0, stream>>>(x2b16, nrm, cd);
    knn_merge_kernel<8><<<256, 64, 0, stream>>>(cd, idx);
    block2_fused_kernel<<<BSZ * NPT / 16, 512, 0, stream>>>(x2b16, idx, w1t, h2b1, w2t, h2b2,
                                                            x3b16, nrm);

    knn_mfma_kernel<128, 8><<<kg, 256, 0, stream>>>(x3b16, nrm, cd);
    knn_merge_kernel<8><<<256, 64, 0, stream>>>(cd, idx);
    block3_fused_kernel<<<BSZ * NPT / 8, 512, 0, stream>>>(x3b16, idx, w3t, h3b1, part);

    head2_kernel<<<dim3(48, 8), 128, 0, stream>>>(part, fc1w, fc1b, fc2w, fc2b,
                                                  fc3w, fc3b, out);
}

// Round 18
// 307.827 us; speedup vs baseline: 1.1093x; 1.1093x over previous
//
#include <hip/hip_runtime.h>

#define KNB 16
#define BSZ 8
#define NPT 2048

typedef __attribute__((ext_vector_type(8))) short bf16x8;
typedef __attribute__((ext_vector_type(4))) float f32x4;

// lrelu = max(x, 0.01x): exact for all x, 2 VALU ops (vs cmp+cndmask 3).
__device__ __forceinline__ float lrelu(float x) { return fmaxf(x, 0.01f * x); }

__device__ __forceinline__ unsigned short bf16rne(float f) {
    union { float f; unsigned int u; } v; v.f = f;
    return (unsigned short)((v.u + 0x7FFFu + ((v.u >> 16) & 1u)) >> 16);
}

// pack 2 f32 -> 2 bf16 (lo | hi<<16), RNE — single VALU op, bit-identical
// to bf16rne pair (R23).
__device__ __forceinline__ unsigned int cvt_pk_bf16(float lo, float hi) {
    unsigned int r;
    asm("v_cvt_pk_bf16_f32 %0, %1, %2" : "=v"(r) : "v"(lo), "v"(hi));
    return r;
}

// pack candidate index into low 11 mantissa bits of fp32 score -> unique,
// float-comparable key. idx = bits & 2047.
__device__ __forceinline__ float packkey(float d, int idx) {
    union { float f; unsigned int u; } v; v.f = d;
    v.u = (v.u & 0xFFFFF800u) | (unsigned int)idx;
    return v.f;
}

// ---------------------------------------------------------------------------
// Branch-free top-16 primitives (R15). Keys unique -> no stability issues.
// ---------------------------------------------------------------------------
__device__ __forceinline__ void ceA(float& a, float& b) {
    const float lo = fminf(a, b), hi = fmaxf(a, b);
    a = lo; b = hi;
}

// bitonic sort 16 in-register, ascending. 80 CE = 160 min/max, depth 10.
__device__ __forceinline__ void bsort16(float* c) {
#pragma unroll
    for (int k = 2; k <= 16; k <<= 1) {
#pragma unroll
        for (int j = k >> 1; j > 0; j >>= 1) {
#pragma unroll
            for (int i = 0; i < 16; ++i) {
                const int l = i ^ j;
                if (l > i) {
                    if ((i & k) == 0) ceA(c[i], c[l]);
                    else              ceA(c[l], c[i]);
                }
            }
        }
    }
}

// L sorted asc, C sorted asc -> L = 16 smallest of union, sorted asc.
__device__ __forceinline__ void merge16(float* L, const float* C) {
#pragma unroll
    for (int i = 0; i < 16; ++i) L[i] = fminf(L[i], C[15 - i]);
#pragma unroll
    for (int j = 8; j > 0; j >>= 1) {
#pragma unroll
        for (int i = 0; i < 16; ++i) {
            const int l = i ^ j;
            if (l > i) ceA(L[i], L[l]);
        }
    }
}

__device__ __forceinline__ void st16(float* dst, const float* L) {
#pragma unroll
    for (int c = 0; c < 4; ++c)
        *(f32x4*)(dst + c * 4) = (f32x4){L[c * 4], L[c * 4 + 1], L[c * 4 + 2], L[c * 4 + 3]};
}

__device__ __forceinline__ void ld16(float* L, const float* src) {
#pragma unroll
    for (int c = 0; c < 4; ++c) {
        const f32x4 v = *(const f32x4*)(src + c * 4);
        L[c * 4] = v[0]; L[c * 4 + 1] = v[1]; L[c * 4 + 2] = v[2]; L[c * 4 + 3] = v[3];
    }
}

// cross-wave merge of 4 sorted lists (rows = lanes) + writeout by wave 0.
__device__ __forceinline__ void xwave_merge_out(float (*sS)[20], int w, int lane,
                                                float* L, float* outp) {
    st16(sS[w * 64 + lane], L);
    __syncthreads();
    if ((w & 1) == 0) {
        float C[16];
        ld16(C, sS[(w + 1) * 64 + lane]);
        merge16(L, C);
        if (w == 2) st16(sS[2 * 64 + lane], L);
    }
    __syncthreads();
    if (w == 0) {
        float C[16];
        ld16(C, sS[2 * 64 + lane]);
        merge16(L, C);
        st16(outp, L);
    }
}

// ---------------------------------------------------------------------------
// Merged weight prep (R18).
// ---------------------------------------------------------------------------
__global__ void wprep_all_kernel(const float* __restrict__ h2w1, unsigned short* __restrict__ w1t,
                                 const float* __restrict__ h2w2, unsigned short* __restrict__ w2t,
                                 const float* __restrict__ h3w1, unsigned short* __restrict__ w3t,
                                 const float* __restrict__ w1, const float* __restrict__ w2,
                                 const float* __restrict__ w3,
                                 unsigned short* __restrict__ w1a, unsigned short* __restrict__ w2a,
                                 unsigned short* __restrict__ w3a) {
    const int bid = blockIdx.x, tid = threadIdx.x;
    if (bid < 64) {
        int i = bid * 256 + tid;                 // K=64, N=256
        int k = i >> 8, n = i & 255;
        w1t[n * 64 + k] = bf16rne(h2w1[i]);
    } else if (bid < 192) {
        int i = (bid - 64) * 256 + tid;          // K=256, N=128
        int k = i >> 7, n = i & 127;
        w2t[n * 256 + k] = bf16rne(h2w2[i]);
    } else if (bid < 320) {
        int i = (bid - 192) * 256 + tid;
        int k = i >> 7, n = i & 127;
        w3t[n * 256 + k] = bf16rne(h3w1[i]);
    } else {
        int i = (bid - 320) * 256 + tid;
        if (i < 512) {
            int n = i >> 5, k = i & 31;
            w1a[i] = (k < 6) ? bf16rne(w1[k * 16 + n]) : (unsigned short)0;
        } else if (i < 2560) {
            int j = i - 512, n = j >> 5, k = j & 31;
            w2a[j] = (k < 16) ? bf16rne(w2[k * 64 + n]) : (unsigned short)0;
        } else if (i < 4608) {
            int j = i - 2560, n = j >> 6, k = j & 63;
            w3a[j] = bf16rne(w3[k * 32 + n]);
        }
    }
}

// ---------------------------------------------------------------------------
// Per-point squared norms (x only; x2/x3 norms are fused into block1/block2)
// ---------------------------------------------------------------------------
template<int C>
__global__ void norms_kernel(const float* __restrict__ feat, float* __restrict__ out) {
    int gid = blockIdx.x * blockDim.x + threadIdx.x;
    if (gid < BSZ * NPT) {
        const float* p = feat + (size_t)gid * C;
        float s = 0.f;
#pragma unroll
        for (int c = 0; c < C; ++c) s = fmaf(p[c], p[c], s);
        out[gid] = s;
    }
}

// ---------------------------------------------------------------------------
// KNN C=3, fp32 (R20 XCD-batch swizzle).
// ---------------------------------------------------------------------------
template<int JS>
__launch_bounds__(256, 4)
__global__ void knn3_kernel(const float* __restrict__ feat,
                            const float* __restrict__ norms,
                            float* __restrict__ cand) {
    constexpr int JL = NPT / JS;
    constexpr int JP = JL / 4;
    const int idxf = blockIdx.x + 32 * (blockIdx.y + 8 * blockIdx.z);
    const int b    = idxf & 7;
    const int rem  = idxf >> 3;          // 0..255
    const int js   = rem & 7;
    const int i0   = (rem >> 3) * 64;
    const int t = threadIdx.x, w = t >> 6, lane = t & 63;
    const float* fb = feat + (size_t)b * NPT * 3;
    const float* nb = norms + (size_t)b * NPT;

    __shared__ __align__(16) float sS[256][20];

    float q0, q1, q2;
    { const float* qp = fb + (size_t)(i0 + lane) * 3; q0 = qp[0]; q1 = qp[1]; q2 = qp[2]; }

    float L[16];
    const int jbeg = js * JL + w * JP;
#pragma unroll 1
    for (int j0 = jbeg; j0 < jbeg + JP; j0 += 16) {
        float C[16];
#pragma unroll
        for (int u = 0; u < 16; ++u) {
            const int j = j0 + u;
            const float* pp = fb + (size_t)j * 3;
            C[u] = packkey(fmaf(-2.f, fmaf(q0, pp[0], fmaf(q1, pp[1], q2 * pp[2])), nb[j]), j);
        }
        bsort16(C);
        if (j0 == jbeg) {
#pragma unroll
            for (int u = 0; u < 16; ++u) L[u] = C[u];
        } else {
            merge16(L, C);
        }
    }
    float* o = cand + (((size_t)b * NPT + i0 + lane) * JS + js) * 16;
    xwave_merge_out(sS, w, lane, L, o);
}

// ---------------------------------------------------------------------------
// KNN via bf16 MFMA (R20 XCD-batch swizzle). R23: C=128 stages the shared
// 64x128 query tile in LDS once. R29: same dedup for C=32 (neutral, kept).
// ---------------------------------------------------------------------------
template<int C, int JS>
__launch_bounds__(256, C == 32 ? 4 : 3)
__global__ void knn_mfma_kernel(const unsigned short* __restrict__ fb16,
                                const float* __restrict__ norms,
                                float* __restrict__ cand) {
    constexpr int JL = NPT / JS;
    constexpr int KS = C / 32;
    const int idxf = blockIdx.x + 32 * (blockIdx.y + 8 * blockIdx.z);
    const int b    = idxf & 7;
    const int rem  = idxf >> 3;          // 0..255
    const int js   = rem & 7;
    const int i0   = (rem >> 3) * 64;
    const int t    = threadIdx.x;
    const int w    = t >> 6;
    const int lane = t & 63;
    const int l15  = lane & 15;
    const int quad = lane >> 4;
    const unsigned short* fbb = fb16 + (size_t)b * NPT * C;
    const float* nb = norms + (size_t)b * NPT;

    __shared__ __align__(16) float sS[256][20];

    bf16x8 afr[KS * 4];
    if constexpr (C == 128) {
        __shared__ __align__(16) unsigned short sAF[64][132];   // 16896 B
        {
            const int row = t >> 2, c4 = t & 3;
#pragma unroll
            for (int c = 0; c < 4; ++c) {
                const int chunk = c4 * 4 + c;
                *(bf16x8*)&sAF[row][chunk * 8] =
                    *(const bf16x8*)(fbb + (size_t)(i0 + row) * 128 + chunk * 8);
            }
        }
        __syncthreads();
#pragma unroll
        for (int ks = 0; ks < KS; ++ks)
#pragma unroll
            for (int mi = 0; mi < 4; ++mi)
                afr[ks * 4 + mi] = *(const bf16x8*)&sAF[mi * 16 + l15][ks * 32 + quad * 8];
    } else {
        // R29: stage 64x32 query tile once (256 threads x 16B = 4KB)
        __shared__ __align__(16) unsigned short sQ[64][40];     // 5120 B
        {
            const int row = t >> 2, c4 = t & 3;
            *(bf16x8*)&sQ[row][c4 * 8] =
                *(const bf16x8*)(fbb + (size_t)(i0 + row) * 32 + c4 * 8);
        }
        __syncthreads();
#pragma unroll
        for (int mi = 0; mi < 4; ++mi)
            afr[mi] = *(const bf16x8*)&sQ[mi * 16 + l15][quad * 8];
    }

    float L[16];
    const int jbeg = js * JL;
#pragma unroll 1
    for (int j0 = jbeg; j0 < jbeg + JL; j0 += 64) {
        f32x4 acc[4];
#pragma unroll
        for (int mi = 0; mi < 4; ++mi) acc[mi] = (f32x4){0.f, 0.f, 0.f, 0.f};
        const unsigned short* prow = fbb + (size_t)(j0 + w * 16 + l15) * C + quad * 8;
#pragma unroll
        for (int ks = 0; ks < KS; ++ks) {
            const bf16x8 bfr = *(const bf16x8*)(prow + ks * 32);
#pragma unroll
            for (int mi = 0; mi < 4; ++mi)
                acc[mi] = __builtin_amdgcn_mfma_f32_16x16x32_bf16(afr[ks * 4 + mi], bfr, acc[mi], 0, 0, 0);
        }
        const float nv  = nb[j0 + w * 16 + l15];
        const int  cidx = j0 + w * 16 + l15;
        // D layout: col(candidate)=l15, row(query)=mi*16+quad*4+r. Write
        // packed keys to this wave's private strip; read back transposed.
#pragma unroll
        for (int mi = 0; mi < 4; ++mi)
#pragma unroll
            for (int r = 0; r < 4; ++r)
                sS[w * 64 + mi * 16 + quad * 4 + r][l15] = packkey(fmaf(-2.f, acc[mi][r], nv), cidx);
        float Cb[16];
        ld16(Cb, sS[w * 64 + lane]);
        bsort16(Cb);
        if (j0 == jbeg) {
#pragma unroll
            for (int u = 0; u < 16; ++u) L[u] = Cb[u];
        } else {
            merge16(L, Cb);
        }
    }

    float* o = cand + (((size_t)b * NPT + i0 + lane) * JS + js) * 16;
    xwave_merge_out(sS, w, lane, L, o);
}

// ---------------------------------------------------------------------------
// Merge JS sorted packed-key lists per query -> final top-16 indices.
// ---------------------------------------------------------------------------
template<int JS>
__launch_bounds__(64)
__global__ void knn_merge_kernel(const float* __restrict__ cand, int* __restrict__ knn_out) {
    const int q = blockIdx.x * 64 + threadIdx.x;
    const float* pd = cand + (size_t)q * JS * 16;
    float L[16];
    ld16(L, pd);
#pragma unroll
    for (int s = 1; s < JS; ++s) {
        float C[16];
        ld16(C, pd + s * 16);
        merge16(L, C);
    }
    int* o = knn_out + (size_t)q * KNB;
#pragma unroll
    for (int u = 0; u < 16; ++u) {
        union { float f; unsigned int v; } z; z.f = L[u];
        o[u] = (int)(z.v & 2047u);
    }
}

// ---------------------------------------------------------------------------
// Block 1 via MFMA, swapped operands (R18) + fused x2 norm.
// R23: bf16 packing via v_cvt_pk_bf16_f32 (1 op per pair, bit-identical).
// ---------------------------------------------------------------------------
__launch_bounds__(256, 3)
__global__ void block1_mfma_kernel(const float* __restrict__ x, const int* __restrict__ knn,
                                   const unsigned short* __restrict__ w1a, const float* __restrict__ b1,
                                   const unsigned short* __restrict__ w2a, const float* __restrict__ b2,
                                   const unsigned short* __restrict__ w3a, const float* __restrict__ b3,
                                   unsigned short* __restrict__ x2b, float* __restrict__ nrm) {
    const int w = threadIdx.x >> 6, lane = threadIdx.x & 63;
    const int l15 = lane & 15, quad = lane >> 4;

    const bf16x8 W1 = *(const bf16x8*)(w1a + l15 * 32 + quad * 8);
    bf16x8 W2[4];
#pragma unroll
    for (int nt = 0; nt < 4; ++nt)
        W2[nt] = *(const bf16x8*)(w2a + (nt * 16 + l15) * 32 + quad * 8);
    bf16x8 W3[2][2];
#pragma unroll
    for (int tt = 0; tt < 2; ++tt)
#pragma unroll
        for (int ks = 0; ks < 2; ++ks)
            W3[tt][ks] = *(const bf16x8*)(w3a + (tt * 16 + l15) * 64 + ks * 32 + quad * 8);
    float b1v[4], b2v[4][4], b3v[2][4];
#pragma unroll
    for (int r = 0; r < 4; ++r) b1v[r] = b1[quad * 4 + r];
#pragma unroll
    for (int nt = 0; nt < 4; ++nt)
#pragma unroll
        for (int r = 0; r < 4; ++r) b2v[nt][r] = b2[nt * 16 + quad * 4 + r];
#pragma unroll
    for (int tt = 0; tt < 2; ++tt)
#pragma unroll
        for (int r = 0; r < 4; ++r) b3v[tt][r] = b3[tt * 16 + quad * 4 + r];

    const int src0 = ((2 * quad) & 3) * 16 + l15;
    const int src1 = ((2 * quad + 1) & 3) * 16 + l15;
    const int ntsel = quad >> 1;

    const int p0 = blockIdx.x * 8 + w * 2;
#pragma unroll 2
    for (int pi = 0; pi < 2; ++pi) {
        const int p = p0 + pi, b = p >> 11, n = p & (NPT - 1);
        int d0 = 0, d1 = 0, d2 = 0;
        if (quad == 0) {
            const float* xc = x + ((size_t)b * NPT + n) * 3;
            const int jn = knn[(size_t)p * KNB + l15];
            const float* xn = x + ((size_t)b * NPT + jn) * 3;
            const unsigned s0 = bf16rne(xc[0]), s1 = bf16rne(xc[1]), s2 = bf16rne(xc[2]);
            const unsigned s3 = bf16rne(xn[0]), s4 = bf16rne(xn[1]), s5 = bf16rne(xn[2]);
            d0 = (int)(s0 | (s1 << 16));
            d1 = (int)(s2 | (s3 << 16));
            d2 = (int)(s4 | (s5 << 16));
        }
        union { int i[4]; bf16x8 v; } B1;
        B1.i[0] = d0; B1.i[1] = d1; B1.i[2] = d2; B1.i[3] = 0;
        const f32x4 a1 = __builtin_amdgcn_mfma_f32_16x16x32_bf16(W1, B1.v, (f32x4){0.f, 0.f, 0.f, 0.f}, 0, 0, 0);

        const int h10 = (int)cvt_pk_bf16(lrelu(a1[0] + b1v[0]), lrelu(a1[1] + b1v[1]));
        const int h11 = (int)cvt_pk_bf16(lrelu(a1[2] + b1v[2]), lrelu(a1[3] + b1v[3]));
        union { int i[4]; bf16x8 v; } B2;
        {
            const int e0 = __shfl(h10, src0), e1 = __shfl(h11, src0);
            const int e2 = __shfl(h10, src1), e3 = __shfl(h11, src1);
            const bool val = quad < 2;
            B2.i[0] = val ? e0 : 0; B2.i[1] = val ? e1 : 0;
            B2.i[2] = val ? e2 : 0; B2.i[3] = val ? e3 : 0;
        }
        f32x4 a2[4];
#pragma unroll
        for (int nt = 0; nt < 4; ++nt)
            a2[nt] = __builtin_amdgcn_mfma_f32_16x16x32_bf16(W2[nt], B2.v, (f32x4){0.f, 0.f, 0.f, 0.f}, 0, 0, 0);
        int dpk[4][2];
#pragma unroll
        for (int nt = 0; nt < 4; ++nt) {
            dpk[nt][0] = (int)cvt_pk_bf16(lrelu(a2[nt][0] + b2v[nt][0]), lrelu(a2[nt][1] + b2v[nt][1]));
            dpk[nt][1] = (int)cvt_pk_bf16(lrelu(a2[nt][2] + b2v[nt][2]), lrelu(a2[nt][3] + b2v[nt][3]));
        }
        f32x4 a3[2] = { (f32x4){0.f, 0.f, 0.f, 0.f}, (f32x4){0.f, 0.f, 0.f, 0.f} };
#pragma unroll
        for (int ks = 0; ks < 2; ++ks) {
            union { int i[4]; bf16x8 v; } B3;
            const int a0l = __shfl(dpk[2 * ks][0], src0), a0h = __shfl(dpk[2 * ks + 1][0], src0);
            const int a1l = __shfl(dpk[2 * ks][1], src0), a1h = __shfl(dpk[2 * ks + 1][1], src0);
            const int a2l = __shfl(dpk[2 * ks][0], src1), a2h = __shfl(dpk[2 * ks + 1][0], src1);
            const int a3l = __shfl(dpk[2 * ks][1], src1), a3h = __shfl(dpk[2 * ks + 1][1], src1);
            B3.i[0] = ntsel ? a0h : a0l;
            B3.i[1] = ntsel ? a1h : a1l;
            B3.i[2] = ntsel ? a2h : a2l;
            B3.i[3] = ntsel ? a3h : a3l;
#pragma unroll
            for (int tt = 0; tt < 2; ++tt)
                a3[tt] = __builtin_amdgcn_mfma_f32_16x16x32_bf16(W3[tt][ks], B3.v, a3[tt], 0, 0, 0);
        }
        float na = 0.f;
#pragma unroll
        for (int tt = 0; tt < 2; ++tt) {
#pragma unroll
            for (int r = 0; r < 4; ++r) {
                float s = lrelu(a3[tt][r] + b3v[tt][r]);
                s += __shfl_xor(s, 1);
                s += __shfl_xor(s, 2);
                s += __shfl_xor(s, 4);
                s += __shfl_xor(s, 8);
                na = fmaf(s, s, na);                      // all lanes hold s
                if (l15 == 0)
                    x2b[(size_t)p * 32 + tt * 16 + quad * 4 + r] = bf16rne(s);
            }
        }
        // fused norm: na is quad-partial (8 channels), identical across l15
        na += __shfl_xor(na, 16);
        na += __shfl_xor(na, 32);
        if (lane == 0) nrm[p] = na;
    }
}

// ---------------------------------------------------------------------------
// Block 2 fused, weight-stationary, 8-wave, LDS-staged gathers (R22),
// operand-swapped L1 + pad-buffer tail (R25), (512,4) optimum (R28),
// paired points + 4 sH1 buffers (R30: barriers 17 -> 10).
// ---------------------------------------------------------------------------
__launch_bounds__(512, 4)
__global__ void block2_fused_kernel(const unsigned short* __restrict__ x2b,
                                    const int* __restrict__ knn,
                                    const unsigned short* __restrict__ w1t,  // [256][64]
                                    const float* __restrict__ b1,
                                    const unsigned short* __restrict__ w2t,  // [128][256]
                                    const float* __restrict__ b2,
                                    unsigned short* __restrict__ x3b,
                                    float* __restrict__ nrm2) {
    const int w    = threadIdx.x >> 6;        // 0..7
    const int lane = threadIdx.x & 63;
    const int l15  = lane & 15, quad = lane >> 4;
    __shared__ __align__(16) unsigned short sH1[4][16][264];   // 33792 B
    __shared__ __align__(16) unsigned short sA2[16][17][40];   // 21760 B (pads = us buffer)

    bf16x8 B1[2][2];
#pragma unroll
    for (int nt2 = 0; nt2 < 2; ++nt2)
#pragma unroll
        for (int ks = 0; ks < 2; ++ks)
            B1[nt2][ks] = *(const bf16x8*)(w1t + (size_t)(w * 32 + nt2 * 16 + l15) * 64 + ks * 32 + quad * 8);
    bf16x8 B2[8];
#pragma unroll
    for (int ks = 0; ks < 8; ++ks)
        B2[ks] = *(const bf16x8*)(w2t + (size_t)(w * 16 + l15) * 256 + ks * 32 + quad * 8);
    // bias indexed by D-row (quad*4+r) after operand swap
    float bA[2][4];
#pragma unroll
    for (int nt2 = 0; nt2 < 2; ++nt2)
#pragma unroll
        for (int r = 0; r < 4; ++r) bA[nt2][r] = b1[w * 32 + nt2 * 16 + quad * 4 + r];
    const float b2v = b2[w * 16 + l15];

    const int src = (blockIdx.x & 7) * 128 + (blockIdx.x >> 3);   // XCD-batch swizzle
    const int p0 = src * 16;                             // 16 points, same batch
    const unsigned short* xb = x2b + (size_t)(p0 >> 11) * NPT * 32;

    // ---- stage: wave w loads points 2w, 2w+1's rows into LDS, once --------
    {
        const int pA = p0 + 2 * w, pB = pA + 1;
        const int nA = knn[(size_t)pA * KNB + l15];
        const int nB = knn[(size_t)pB * KNB + l15];
        *(bf16x8*)&sA2[2 * w][l15][quad * 8] =
            *(const bf16x8*)(xb + (size_t)nA * 32 + quad * 8);
        *(bf16x8*)&sA2[2 * w + 1][l15][quad * 8] =
            *(const bf16x8*)(xb + (size_t)nB * 32 + quad * 8);
        if (l15 == 0) {
            *(bf16x8*)&sA2[2 * w][16][quad * 8] =
                *(const bf16x8*)(x2b + (size_t)pA * 32 + quad * 8);
            *(bf16x8*)&sA2[2 * w + 1][16][quad * 8] =
                *(const bf16x8*)(x2b + (size_t)pB * 32 + quad * 8);
        }
    }
    __syncthreads();                                     // sA2 ready (cols 0..31 read-only after)

    const int nrow = (w * 16 + l15) >> 3;                // pad row for this lane's channel
    const int ncol = 32 + (l15 & 7);                     // pad col

#pragma unroll 1
    for (int pp = 0; pp < 8; ++pp) {
        const int bufA = (pp & 1) * 2, bufB = bufA + 1;  // pairs {0,1} / {2,3}
        const int piA = 2 * pp, piB = piA + 1;

        // ---- L1 phase: both points of the pair (independent MFMA work) ----
        {
            const bf16x8 a0 = *(const bf16x8*)&sA2[piA][16][quad * 8];
            const bf16x8 a1 = *(const bf16x8*)&sA2[piA][l15][quad * 8];
#pragma unroll
            for (int nt2 = 0; nt2 < 2; ++nt2) {
                f32x4 acc = (f32x4){0.f, 0.f, 0.f, 0.f};
                acc = __builtin_amdgcn_mfma_f32_16x16x32_bf16(B1[nt2][0], a0, acc, 0, 0, 0);
                acc = __builtin_amdgcn_mfma_f32_16x16x32_bf16(B1[nt2][1], a1, acc, 0, 0, 0);
                const unsigned int u01 = cvt_pk_bf16(lrelu(acc[0] + bA[nt2][0]), lrelu(acc[1] + bA[nt2][1]));
                const unsigned int u23 = cvt_pk_bf16(lrelu(acc[2] + bA[nt2][2]), lrelu(acc[3] + bA[nt2][3]));
                union { unsigned int u[2]; unsigned long long ull; } pk;
                pk.u[0] = u01; pk.u[1] = u23;
                *(unsigned long long*)&sH1[bufA][l15][w * 32 + nt2 * 16 + quad * 4] = pk.ull;
            }
        }
        {
            const bf16x8 a0 = *(const bf16x8*)&sA2[piB][16][quad * 8];
            const bf16x8 a1 = *(const bf16x8*)&sA2[piB][l15][quad * 8];
#pragma unroll
            for (int nt2 = 0; nt2 < 2; ++nt2) {
                f32x4 acc = (f32x4){0.f, 0.f, 0.f, 0.f};
                acc = __builtin_amdgcn_mfma_f32_16x16x32_bf16(B1[nt2][0], a0, acc, 0, 0, 0);
                acc = __builtin_amdgcn_mfma_f32_16x16x32_bf16(B1[nt2][1], a1, acc, 0, 0, 0);
                const unsigned int u01 = cvt_pk_bf16(lrelu(acc[0] + bA[nt2][0]), lrelu(acc[1] + bA[nt2][1]));
                const unsigned int u23 = cvt_pk_bf16(lrelu(acc[2] + bA[nt2][2]), lrelu(acc[3] + bA[nt2][3]));
                union { unsigned int u[2]; unsigned long long ull; } pk;
                pk.u[0] = u01; pk.u[1] = u23;
                *(unsigned long long*)&sH1[bufB][l15][w * 32 + nt2 * 16 + quad * 4] = pk.ull;
            }
        }

        __syncthreads();                                 // ONE barrier per pair

        // ---- L2 phase: both points (sequential, register reuse) -----------
        {
            bf16x8 afA[4], afB[4];
#pragma unroll
            for (int ks = 0; ks < 4; ++ks)
                afA[ks] = *(const bf16x8*)&sH1[bufA][l15][ks * 32 + quad * 8];
#pragma unroll
            for (int ks = 0; ks < 4; ++ks)
                afB[ks] = *(const bf16x8*)&sH1[bufA][l15][128 + ks * 32 + quad * 8];
            f32x4 accA = (f32x4){0.f, 0.f, 0.f, 0.f}, accB = (f32x4){0.f, 0.f, 0.f, 0.f};
#pragma unroll
            for (int ks = 0; ks < 4; ++ks) {
                accA = __builtin_amdgcn_mfma_f32_16x16x32_bf16(afA[ks], B2[ks], accA, 0, 0, 0);
                accB = __builtin_amdgcn_mfma_f32_16x16x32_bf16(afB[ks], B2[4 + ks], accB, 0, 0, 0);
            }
            float s = 0.f;
#pragma unroll
            for (int r = 0; r < 4; ++r) s += lrelu(accA[r] + accB[r] + b2v);
            s += __shfl_xor(s, 16);
            s += __shfl_xor(s, 32);
            const unsigned short us = bf16rne(s);
            if (quad == 0) sA2[piA][nrow][ncol] = us;     // us -> dead pad bytes
        }
        {
            bf16x8 afA[4], afB[4];
#pragma unroll
            for (int ks = 0; ks < 4; ++ks)
                afA[ks] = *(const bf16x8*)&sH1[bufB][l15][ks * 32 + quad * 8];
#pragma unroll
            for (int ks = 0; ks < 4; ++ks)
                afB[ks] = *(const bf16x8*)&sH1[bufB][l15][128 + ks * 32 + quad * 8];
            f32x4 accA = (f32x4){0.f, 0.f, 0.f, 0.f}, accB = (f32x4){0.f, 0.f, 0.f, 0.f};
#pragma unroll
            for (int ks = 0; ks < 4; ++ks) {
                accA = __builtin_amdgcn_mfma_f32_16x16x32_bf16(afA[ks], B2[ks], accA, 0, 0, 0);
                accB = __builtin_amdgcn_mfma_f32_16x16x32_bf16(afB[ks], B2[4 + ks], accB, 0, 0, 0);
            }
            float s = 0.f;
#pragma unroll
            for (int r = 0; r < 4; ++r) s += lrelu(accA[r] + accB[r] + b2v);
            s += __shfl_xor(s, 16);
            s += __shfl_xor(s, 32);
            const unsigned short us = bf16rne(s);
            if (quad == 0) sA2[piB][nrow][ncol] = us;     // us -> dead pad bytes
        }
    }

    // ---- tail: x3b store (b128) + x3 norm, both from sA2 pads -------------
    __syncthreads();
    if (threadIdx.x < 256) {
        const int pi = threadIdx.x >> 4, seg = threadIdx.x & 15;
        const bf16x8 v = *(const bf16x8*)&sA2[pi][seg][32];   // 8 ch, b128, aligned
        *(bf16x8*)&x3b[(size_t)(p0 + pi) * 128 + seg * 8] = v;
        float s = 0.f;
#pragma unroll
        for (int j = 0; j < 8; ++j) {
            union { unsigned int u; float f; } t;
            t.u = ((unsigned int)(unsigned short)v[j]) << 16;
            s = fmaf(t.f, t.f, s);
        }
        s += __shfl_xor(s, 1);
        s += __shfl_xor(s, 2);
        s += __shfl_xor(s, 4);
        s += __shfl_xor(s, 8);
        if (seg == 0) nrm2[p0 + pi] = s;
    }
}

// ---------------------------------------------------------------------------
// Block 3 fused, R21 LDS-staged gathers + R31 fused running-max (keeps the
// x4-traffic savings). Writes one 128-float partial-max row per block.
// ---------------------------------------------------------------------------
__launch_bounds__(512, 4)
__global__ void block3_fused_kernel(const unsigned short* __restrict__ x3b,
                                    const int* __restrict__ knn,
                                    const unsigned short* __restrict__ w3t,  // [128][256]
                                    const float* __restrict__ bias,
                                    float* __restrict__ part) {
    const int w    = threadIdx.x >> 6;        // 0..7
    const int lane = threadIdx.x & 63;
    const int l15  = lane & 15, quad = lane >> 4;
    // sA[point][row 0..15 = nbr l15, row 16 = center][132 shorts]
    __shared__ __align__(16) unsigned short sA[8][17][132];   // 35904 B

    bf16x8 B3[8];
#pragma unroll
    for (int ks = 0; ks < 8; ++ks)
        B3[ks] = *(const bf16x8*)(w3t + (size_t)(w * 16 + l15) * 256 + ks * 32 + quad * 8);
    const float bv = bias[w * 16 + l15];

    const int src = (blockIdx.x & 7) * 256 + (blockIdx.x >> 3);   // XCD-batch swizzle (2048 blocks)
    const int p0 = src * 8;                              // 8 points, same batch
    const unsigned short* xb = x3b + (size_t)(p0 >> 11) * NPT * 128;

    // ---- stage: wave w loads point (p0+w)'s rows into LDS, exactly once ----
    {
        const int p = p0 + w;
        const int nbr = knn[(size_t)p * KNB + l15];
        const unsigned short* nrow = xb + (size_t)nbr * 128;
#pragma unroll
        for (int c = 0; c < 4; ++c) {
            const bf16x8 v = *(const bf16x8*)(nrow + (c * 4 + quad) * 8);
            *(bf16x8*)&sA[w][l15][(c * 4 + quad) * 8] = v;
        }
        if (quad == 0) {
            const bf16x8 v = *(const bf16x8*)(x3b + (size_t)p * 128 + l15 * 8);
            *(bf16x8*)&sA[w][16][l15 * 8] = v;
        }
    }
    __syncthreads();                                     // the only barrier

    float mx = -1e30f;
#pragma unroll 2
    for (int pi = 0; pi < 8; ++pi) {
        bf16x8 afA[4], afB[4];
#pragma unroll
        for (int ks = 0; ks < 4; ++ks) {
            afA[ks] = *(const bf16x8*)&sA[pi][16][(ks * 4 + quad) * 8];    // center (broadcast)
            afB[ks] = *(const bf16x8*)&sA[pi][l15][(ks * 4 + quad) * 8];   // neighbor rows
        }
        f32x4 accA = (f32x4){0.f, 0.f, 0.f, 0.f}, accB = (f32x4){0.f, 0.f, 0.f, 0.f};
#pragma unroll
        for (int ks = 0; ks < 4; ++ks) {
            accA = __builtin_amdgcn_mfma_f32_16x16x32_bf16(afA[ks], B3[ks], accA, 0, 0, 0);
            accB = __builtin_amdgcn_mfma_f32_16x16x32_bf16(afB[ks], B3[4 + ks], accB, 0, 0, 0);
        }
        float s = 0.f;
#pragma unroll
        for (int r = 0; r < 4; ++r) s += lrelu(accA[r] + accB[r] + bv);
        s += __shfl_xor(s, 16);
        s += __shfl_xor(s, 32);
        mx = fmaxf(mx, s);                               // all lanes hold s
    }
    if (quad == 0) part[(size_t)src * 128 + w * 16 + l15] = mx;
}

// ---------------------------------------------------------------------------
// R32: stage-2 max reduce — 2048x128 partials -> 256x128 (32/batch).
// Restores head2's cheap 32-iteration reduce (R31's 256-iter reduce in
// head2 was latency-bound at occ 8%: 75-81us). fmaxf exact -> bit-identical.
// ---------------------------------------------------------------------------
__launch_bounds__(128)
__global__ void maxpool2_kernel(const float* __restrict__ part,
                                float* __restrict__ part2) {
    const int chunk = blockIdx.x, b = blockIdx.y, t = threadIdx.x;
    const float* pb = part + ((size_t)b * 256 + (size_t)chunk * 8) * 128;
    float m = -1e30f;
#pragma unroll
    for (int n = 0; n < 8; ++n) m = fmaxf(m, pb[(size_t)n * 128 + t]);
    part2[((size_t)b * 32 + chunk) * 128 + t] = m;
}

// ---------------------------------------------------------------------------
// Head stage 2 (32 partials per batch, as R30)
// ---------------------------------------------------------------------------
__launch_bounds__(128)
__global__ void head2_kernel(const float* __restrict__ part2,
                             const float* __restrict__ fc1w, const float* __restrict__ fc1b,
                             const float* __restrict__ fc2w, const float* __restrict__ fc2b,
                             const float* __restrict__ fc3w, const float* __restrict__ fc3b,
                             float* __restrict__ out) {
    const int g = blockIdx.x, b = blockIdx.y, t = threadIdx.x;
    __shared__ float s5[128], s6[128], s7[128];
    float m = -1e30f;
#pragma unroll
    for (int c = 0; c < 32; ++c)
        m = fmaxf(m, part2[((size_t)b * 32 + c) * 128 + t]);
    s5[t] = m;
    __syncthreads();
    float a = fc1b[t];
#pragma unroll 4
    for (int i = 0; i < 128; ++i) a = fmaf(s5[i], fc1w[i * 128 + t], a);
    s6[t] = lrelu(a);
    __syncthreads();
    a = fc2b[t];
#pragma unroll 4
    for (int i = 0; i < 128; ++i) a = fmaf(s6[i], fc2w[i * 128 + t], a);
    s7[t] = lrelu(a);
    __syncthreads();
    const int o = g * 128 + t;
    float acc = fc3b[o];
#pragma unroll 4
    for (int i = 0; i < 128; ++i) acc = fmaf(s7[i], fc3w[(size_t)i * 6144 + o], acc);
    out[(size_t)b * 6144 + o] = acc;
}

// ---------------------------------------------------------------------------
extern "C" void kernel_launch(void* const* d_in, const int* in_sizes, int n_in,
                              void* d_out, int out_size, void* d_ws, size_t ws_size,
                              hipStream_t stream) {
    const float* x    = (const float*)d_in[0];
    const float* h1w1 = (const float*)d_in[1];
    const float* h1b1 = (const float*)d_in[2];
    const float* h1w2 = (const float*)d_in[3];
    const float* h1b2 = (const float*)d_in[4];
    const float* h1w3 = (const float*)d_in[5];
    const float* h1b3 = (const float*)d_in[6];
    const float* h2w1 = (const float*)d_in[7];
    const float* h2b1 = (const float*)d_in[8];
    const float* h2w2 = (const float*)d_in[9];
    const float* h2b2 = (const float*)d_in[10];
    const float* h3w1 = (const float*)d_in[11];
    const float* h3b1 = (const float*)d_in[12];
    const float* fc1w = (const float*)d_in[13];
    const float* fc1b = (const float*)d_in[14];
    const float* fc2w = (const float*)d_in[15];
    const float* fc2b = (const float*)d_in[16];
    const float* fc3w = (const float*)d_in[17];
    const float* fc3b = (const float*)d_in[18];

    float* ws = (float*)d_ws;
    unsigned short* x2b16 = (unsigned short*)ws;              //  524288 sh (262144 fl)
    unsigned short* x3b16 = (unsigned short*)(ws + 262144);   // 2097152 sh (1048576 fl)
    float* cd   = ws + 1310720;                               // 2097152 fl (knn candidates)
    int*   idx  = (int*)(ws + 3407872);                       //  262144 int
    float* nrm  = ws + 3670016;                               //   16384 fl
    unsigned short* w1t = (unsigned short*)(ws + 3702784);    //  16384 sh
    unsigned short* w2t = (unsigned short*)(ws + 3710976);    //  32768 sh
    unsigned short* w3t = (unsigned short*)(ws + 3727360);    //  32768 sh
    unsigned short* w1a = (unsigned short*)(ws + 3743744);    //    512 sh
    unsigned short* w2a = (unsigned short*)(ws + 3744000);    //   2048 sh
    unsigned short* w3a = (unsigned short*)(ws + 3745024);    //   2048 sh
    float* part = ws + 3746048;                               //  262144 fl (2048x128)
    float* part2 = ws + 4008192;                              //   32768 fl (256x128;
                                                              //  ends ~16.2 MB <= ws)
    float* out  = (float*)d_out;

    const dim3 kg(32, 8, 8);   // (qtile, j-split=8, batch) -> 2048 blocks

    wprep_all_kernel<<<338, 256, 0, stream>>>(h2w1, w1t, h2w2, w2t, h3w1, w3t,
                                              h1w1, h1w2, h1w3, w1a, w2a, w3a);

    norms_kernel<3><<<64, 256, 0, stream>>>(x, nrm);
    knn3_kernel<8><<<kg, 256, 0, stream>>>(x, nrm, cd);
    knn_merge_kernel<8><<<256, 64, 0, stream>>>(cd, idx);
    block1_mfma_kernel<<<2048, 256, 0, stream>>>(x, idx, w1a, h1b1, w2a, h1b2, w3a, h1b3,
                                                 x2b16, nrm);

    knn_mfma_kernel<32, 8><<<kg, 256, 0, stream>>>(x2b16, nrm, cd);
    knn_merge_kernel<8><<<256, 64, 0, stream>>>(cd, idx);
    block2_fused_kernel<<<BSZ * NPT / 16, 512, 0, stream>>>(x2b16, idx, w1t, h2b1, w2t, h2b2,
                                                            x3b16, nrm);

    knn_mfma_kernel<128, 8><<<kg, 256, 0, stream>>>(x3b16, nrm, cd);
    knn_merge_kernel<8><<<256, 64, 0, stream>>>(cd, idx);
    block3_fused_kernel<<<BSZ * NPT / 8, 512, 0, stream>>>(x3b16, idx, w3t, h3b1, part);

    maxpool2_kernel<<<dim3(32, 8), 128, 0, stream>>>(part, part2);
    head2_kernel<<<dim3(48, 8), 128, 0, stream>>>(part2, fc1w, fc1b, fc2w, fc2b,
                                                  fc3w, fc3b, out);
}